// Round 1
// baseline (92.464 us; speedup 1.0000x reference)
//
#include <hip/hip_runtime.h>
#include <cstdint>

// ModConv: y[b,o,l] = sum_{i,k} bw[b,o,i,k] * x[b,i,l+k-1],
//   bw = conv_w * s[b,i] * demod[b,o],  s = t@mod_w^T + mod_b + 1,
//   demod = rsqrt(sum_{i,k} (conv_w*s)^2 + 1e-8)
// Single persistent kernel: weights modulated+demodulated into LDS (bf16),
// conv done as 3 shifted bf16 MFMA GEMMs per 128x128 output tile.

namespace {
constexpr int NB = 16, NI = 128, NO = 256, NK = 3, NT = 256, NL = 8192;
constexpr int BM = 128, BN = 128;         // o-tile x l-tile
constexpr int TILES_PER_BLOCK = 8;        // 8192 / (128*8) = 8 chunks
constexpr int XT_OFF = 3 * 128 * 256;     // A: 3 taps * 128 rows * 256B = 98304
constexpr int XT_ROWS = 130;              // BN + 2 halo columns
constexpr int S_OFF = XT_OFF + XT_ROWS * 256;   // 131584
constexpr int D_OFF = S_OFF + 512;
constexpr int SMEM_BYTES = D_OFF + 512;         // 132608 <= 163840
}

typedef __attribute__((ext_vector_type(8))) short bf16x8;   // 8 bf16 = 4 VGPR
typedef __attribute__((ext_vector_type(4))) float f32x4;

__device__ __forceinline__ uint32_t f2bf(float f) {
    uint32_t u = __builtin_bit_cast(uint32_t, f);
    return (u + 0x7fffu + ((u >> 16) & 1u)) >> 16;   // RNE
}

__launch_bounds__(256, 1)
__global__ void modconv(const float* __restrict__ x,
                        const float* __restrict__ tvec,
                        const float* __restrict__ conv_w,
                        const float* __restrict__ mod_w,
                        const float* __restrict__ mod_b,
                        float* __restrict__ out) {
    __shared__ __align__(16) char smem[SMEM_BYTES];
    float* s_sh = reinterpret_cast<float*>(smem + S_OFF);
    float* d_sh = reinterpret_cast<float*>(smem + D_OFF);

    const int tid   = threadIdx.x;
    const int b     = blockIdx.z;
    const int chunk = blockIdx.y;
    const int o0    = blockIdx.x * BM;

    // ---- phase 1: style scale s[i] = dot(t[b], mod_w[i]) + mod_b[i] + 1  (f32)
    if (tid < NI) {
        const float* tp = tvec + b * NT;
        const float* mp = mod_w + tid * NT;
        float acc = mod_b[tid] + 1.0f;
        #pragma unroll 8
        for (int j = 0; j < NT; ++j) acc = fmaf(tp[j], mp[j], acc);
        s_sh[tid] = acc;
    }
    __syncthreads();

    // ---- phase 2: demod[o] = rsqrt(sum_i s_i^2 * sum_k w^2 + 1e-8)  (f32)
    {
        const int o_l = tid >> 1, h = tid & 1;
        const float* cw = conv_w + (size_t)(o0 + o_l) * (NI * NK) + h * 64 * NK;
        float sum = 0.f;
        #pragma unroll 4
        for (int ii = 0; ii < 64; ++ii) {
            float s  = s_sh[h * 64 + ii];
            float w0 = cw[ii * 3 + 0], w1 = cw[ii * 3 + 1], w2 = cw[ii * 3 + 2];
            sum = fmaf(s * s, w0 * w0 + w1 * w1 + w2 * w2, sum);
        }
        sum += __shfl_xor(sum, 1);
        if (h == 0) d_sh[o_l] = rsqrtf(sum + 1e-8f);
    }
    __syncthreads();

    // ---- phase 3: fill A = bw tile into LDS, bf16, XOR-swizzled rows
    //      byte(k,o,i) = k*32768 + o*256 + ((i*2) ^ ((o&7)<<4))
    for (int idx = tid; idx < BM * NI; idx += 256) {
        const int i = idx & (NI - 1);
        const int o = idx >> 7;
        const float* cw = conv_w + ((size_t)(o0 + o) * NI + i) * NK;
        const float m  = s_sh[i] * d_sh[o];
        const int   sw = (i * 2) ^ ((o & 7) << 4);
        #pragma unroll
        for (int k = 0; k < NK; ++k) {
            *reinterpret_cast<uint16_t*>(smem + k * 32768 + o * 256 + sw) =
                (uint16_t)f2bf(cw[k] * m);
        }
    }
    // A made visible by the first in-loop __syncthreads()

    const int lane = tid & 63;
    const int wid  = tid >> 6;
    const int wm   = wid >> 1, wn = wid & 1;     // 2x2 waves, 64x64 each
    const int l16  = lane & 15, lg4 = lane >> 4;
    const int lr   = tid & 15,  ig  = tid >> 4;  // X-transpose loader mapping

    const float* xb  = x + (size_t)b * NI * NL;
    float* outb      = out + ((size_t)b * NO + o0) * NL;

    for (int tile = 0; tile < TILES_PER_BLOCK; ++tile) {
        const int l0 = (chunk * TILES_PER_BLOCK + tile) * BN;
        __syncthreads();   // previous tile's compute done -> Xt reusable

        // ---- stage X^T slab: row r <-> global col (l0-1+r), 128 bf16 (i) per row
        #pragma unroll
        for (int pass = 0; pass < 9; ++pass) {
            const int r = pass * 16 + lr;
            if (r < XT_ROWS) {
                const int lg = l0 - 1 + r;
                uint32_t d0 = 0, d1 = 0, d2 = 0, d3 = 0;
                if (lg >= 0 && lg < NL) {
                    const float* px = xb + (size_t)(ig * 8) * NL + lg;
                    d0 = f2bf(px[0])          | (f2bf(px[(size_t)NL])     << 16);
                    d1 = f2bf(px[2*(size_t)NL]) | (f2bf(px[3*(size_t)NL]) << 16);
                    d2 = f2bf(px[4*(size_t)NL]) | (f2bf(px[5*(size_t)NL]) << 16);
                    d3 = f2bf(px[6*(size_t)NL]) | (f2bf(px[7*(size_t)NL]) << 16);
                }
                *reinterpret_cast<uint4*>(
                    smem + XT_OFF + r * 256 + ((ig * 16) ^ ((r & 7) << 4))) =
                    make_uint4(d0, d1, d2, d3);
            }
        }
        __syncthreads();

        // ---- MFMA: 3 taps x 4 K-chunks, each 16 mfma_f32_16x16x32_bf16
        f32x4 acc[4][4];
        const f32x4 zero = {0.f, 0.f, 0.f, 0.f};
        #pragma unroll
        for (int fm = 0; fm < 4; ++fm)
            #pragma unroll
            for (int fn = 0; fn < 4; ++fn)
                acc[fm][fn] = zero;

        #pragma unroll
        for (int k = 0; k < NK; ++k) {
            #pragma unroll
            for (int kc = 0; kc < 4; ++kc) {
                const int cb = kc * 64 + lg4 * 16;
                bf16x8 af[4], bfr[4];
                #pragma unroll
                for (int fm = 0; fm < 4; ++fm) {
                    const int o = wm * 64 + fm * 16 + l16;
                    af[fm] = *reinterpret_cast<const bf16x8*>(
                        smem + k * 32768 + o * 256 + (cb ^ ((o & 7) << 4)));
                }
                #pragma unroll
                for (int fn = 0; fn < 4; ++fn) {
                    const int r = wn * 64 + fn * 16 + l16 + k;
                    bfr[fn] = *reinterpret_cast<const bf16x8*>(
                        smem + XT_OFF + r * 256 + (cb ^ ((r & 7) << 4)));
                }
                #pragma unroll
                for (int fm = 0; fm < 4; ++fm)
                    #pragma unroll
                    for (int fn = 0; fn < 4; ++fn)
                        acc[fm][fn] = __builtin_amdgcn_mfma_f32_16x16x32_bf16(
                            af[fm], bfr[fn], acc[fm][fn], 0, 0, 0);
            }
        }

        // ---- write C (f32): row = (lane>>4)*4 + j, col = lane&15
        #pragma unroll
        for (int fm = 0; fm < 4; ++fm) {
            #pragma unroll
            for (int fn = 0; fn < 4; ++fn) {
                const int og = wm * 64 + fm * 16 + lg4 * 4;
                const int lg = l0 + wn * 64 + fn * 16 + l16;
                #pragma unroll
                for (int j = 0; j < 4; ++j)
                    outb[(size_t)(og + j) * NL + lg] = acc[fm][fn][j];
            }
        }
    }
}

extern "C" void kernel_launch(void* const* d_in, const int* in_sizes, int n_in,
                              void* d_out, int out_size, void* d_ws, size_t ws_size,
                              hipStream_t stream) {
    const float* x      = (const float*)d_in[0];
    const float* t      = (const float*)d_in[1];
    const float* conv_w = (const float*)d_in[2];
    const float* mod_w  = (const float*)d_in[3];
    const float* mod_b  = (const float*)d_in[4];

    dim3 grid(NO / BM, NL / (BN * TILES_PER_BLOCK), NB);   // (2, 8, 16) = 256 blocks
    modconv<<<grid, 256, 0, stream>>>(x, t, conv_w, mod_w, mod_b, (float*)d_out);
}

// Round 2
// 65.091 us; speedup vs baseline: 1.4205x; 1.4205x over previous
//
#include <hip/hip_runtime.h>
#include <cstdint>

// ModConv: y[b,o,l] = sum_{i,k} bw[b,o,i,k] * x[b,i,l+k-1],
//   bw = conv_w * s[b,i] * demod[b,o],  s = t@mod_w^T + mod_b + 1,
//   demod = rsqrt(sum_{i,k} (conv_w*s)^2 + 1e-8)
// 512-thread blocks, 8 waves (2x4), A-tile (bf16, swizzled) in LDS,
// X^T staged via T14 split: global->regs issued before MFMA of the previous
// tile, regs->LDS after the barrier. XCD-paired block swizzle for x reuse.

namespace {
constexpr int NB = 16, NI = 128, NO = 256, NK = 3, NT = 256, NL = 8192;
constexpr int BM = 128, BN = 128;
constexpr int TPB = 8;                        // tiles per block (8*128 = 1024 cols)
constexpr int XT_OFF = 3 * 128 * 256;         // A: 3 taps * 128 o * 256B = 98304
constexpr int XT_ROWS = 130;                  // BN + 2 halo
constexpr int SMEM_BYTES = XT_OFF + XT_ROWS * 256;   // 131584 <= 163840
constexpr int NPASS = 5;                      // ceil(130/32) staging passes
}

typedef __attribute__((ext_vector_type(8))) short bf16x8;
typedef __attribute__((ext_vector_type(4))) float f32x4;

__device__ __forceinline__ uint32_t f2bf(float f) {
    uint32_t u = __builtin_bit_cast(uint32_t, f);
    return (u + 0x7fffu + ((u >> 16) & 1u)) >> 16;   // RNE
}

__launch_bounds__(512, 2)
__global__ void modconv(const float* __restrict__ x,
                        const float* __restrict__ tvec,
                        const float* __restrict__ conv_w,
                        const float* __restrict__ mod_w,
                        const float* __restrict__ mod_b,
                        float* __restrict__ out) {
    __shared__ __align__(16) char smem[SMEM_BYTES];
    // s/d scratch lives in the (not yet used) XT region
    float* s_sh = reinterpret_cast<float*>(smem + XT_OFF);
    float* d_sh = reinterpret_cast<float*>(smem + XT_OFF + 512);

    const int tid = threadIdx.x;

    // ---- XCD-paired block decode: both o-tiles of one (b,chunk) share bid&7
    const int bid  = blockIdx.x;
    const int xcd  = bid & 7;
    const int slot = bid >> 3;          // [0,32)
    const int g    = xcd + 8 * (slot >> 1);   // [0,128): (b,chunk) group
    const int m    = slot & 1;                // o-tile
    const int b     = g >> 3;
    const int chunk = g & 7;
    const int o0    = m * BM;

    const float* xb = x + (size_t)b * NI * NL;
    float* outb     = out + ((size_t)b * NO + o0) * NL;

    // ---- phase 1: s[i] = dot(t[b], mod_w[i]) + mod_b[i] + 1  (4 thr/i)
    {
        const int i = tid >> 2, q = tid & 3;
        const float* tp = tvec + b * NT + q * 64;
        const float* mp = mod_w + i * NT + q * 64;
        float acc = 0.f;
        #pragma unroll 8
        for (int j = 0; j < 64; ++j) acc = fmaf(tp[j], mp[j], acc);
        acc += __shfl_xor(acc, 1);
        acc += __shfl_xor(acc, 2);
        if (q == 0) s_sh[i] = acc + mod_b[i] + 1.0f;
    }
    __syncthreads();

    // ---- phase 2: demod[o] = rsqrt(sum_i s^2 * sum_k w^2 + 1e-8)  (4 thr/o)
    {
        const int o_l = tid >> 2, q = tid & 3;
        const float* cw = conv_w + (size_t)(o0 + o_l) * (NI * NK) + q * 32 * NK;
        float sum = 0.f;
        #pragma unroll 4
        for (int ii = 0; ii < 32; ++ii) {
            float s  = s_sh[q * 32 + ii];
            float w0 = cw[ii * 3 + 0], w1 = cw[ii * 3 + 1], w2 = cw[ii * 3 + 2];
            sum = fmaf(s * s, w0 * w0 + w1 * w1 + w2 * w2, sum);
        }
        sum += __shfl_xor(sum, 1);
        sum += __shfl_xor(sum, 2);
        if (q == 0) d_sh[o_l] = rsqrtf(sum + 1e-8f);
    }
    __syncthreads();

    // ---- staged X loads (tile data held in regs between issue and ds_write)
    float xr[NPASS][8];
    const int lrow = tid & 31;           // row-within-pass (consecutive lanes
    const int ig   = tid >> 5;           //   -> consecutive l: coalesced)

    auto issue_loads = [&](int l0s) {
        #pragma unroll
        for (int p = 0; p < NPASS; ++p) {
            const int r  = p * 32 + lrow;
            const int lg = l0s - 1 + r;
            const bool ok = (r < XT_ROWS) && (lg >= 0) && (lg < NL);
            const float* px = xb + (size_t)(ig * 8) * NL + lg;
            #pragma unroll
            for (int n = 0; n < 8; ++n)
                xr[p][n] = ok ? px[(size_t)n * NL] : 0.0f;
        }
    };
    auto write_stage = [&]() {
        #pragma unroll
        for (int p = 0; p < NPASS; ++p) {
            const int r = p * 32 + lrow;
            if (r < XT_ROWS) {
                uint32_t d0 = f2bf(xr[p][0]) | (f2bf(xr[p][1]) << 16);
                uint32_t d1 = f2bf(xr[p][2]) | (f2bf(xr[p][3]) << 16);
                uint32_t d2 = f2bf(xr[p][4]) | (f2bf(xr[p][5]) << 16);
                uint32_t d3 = f2bf(xr[p][6]) | (f2bf(xr[p][7]) << 16);
                *reinterpret_cast<uint4*>(
                    smem + XT_OFF + r * 256 + ((ig * 16) ^ ((r & 15) << 4))) =
                    make_uint4(d0, d1, d2, d3);
            }
        }
    };

    const int l0_base = chunk * TPB * BN;
    issue_loads(l0_base);   // tile-0 loads fly under the A-fill compute

    // ---- phase 3: A tile (modulated+demodulated weights) -> LDS bf16
    //      byte(k,o,i) = k*32768 + o*256 + ((i*2) ^ ((o&15)<<4)), 2 i per write
    for (int idx = tid; idx < BM * (NI / 2); idx += 512) {
        const int i2 = idx & 63, o = idx >> 6;
        const float* cw = conv_w + ((size_t)(o0 + o) * NI + i2 * 2) * NK;
        const float dm = d_sh[o];
        const float mA = s_sh[i2 * 2] * dm, mB = s_sh[i2 * 2 + 1] * dm;
        const int base = o * 256, sw = (o & 15) << 4;
        #pragma unroll
        for (int k = 0; k < NK; ++k) {
            uint32_t v = f2bf(cw[k] * mA) | (f2bf(cw[k + NK] * mB) << 16);
            *reinterpret_cast<uint32_t*>(
                smem + k * 32768 + base + ((i2 * 4) ^ sw)) = v;
        }
    }
    __syncthreads();        // s/d consumed, A visible
    write_stage();          // XT <- tile 0
    __syncthreads();

    const int lane = tid & 63;
    const int wid  = tid >> 6;
    const int wm   = wid >> 2, wn = wid & 3;   // 2x4 waves: 64x32 out each
    const int l16  = lane & 15, lg4 = lane >> 4;

    for (int tile = 0; tile < TPB; ++tile) {
        const int l0 = l0_base + tile * BN;

        if (tile + 1 < TPB) issue_loads(l0 + BN);   // t+1 loads fly under MFMA

        // ---- MFMA: 3 taps x 4 K-chunks; wave tile 64(o) x 32(l)
        f32x4 acc[4][2];
        const f32x4 zero = {0.f, 0.f, 0.f, 0.f};
        #pragma unroll
        for (int fm = 0; fm < 4; ++fm)
            #pragma unroll
            for (int fn = 0; fn < 2; ++fn) acc[fm][fn] = zero;

        #pragma unroll
        for (int k = 0; k < NK; ++k) {
            #pragma unroll
            for (int kc = 0; kc < 4; ++kc) {
                const int cb = kc * 64 + lg4 * 16;
                bf16x8 af[4], bfr[2];
                #pragma unroll
                for (int fm = 0; fm < 4; ++fm) {
                    const int o = wm * 64 + fm * 16 + l16;
                    af[fm] = *reinterpret_cast<const bf16x8*>(
                        smem + k * 32768 + o * 256 + (cb ^ ((o & 15) << 4)));
                }
                #pragma unroll
                for (int fn = 0; fn < 2; ++fn) {
                    const int r = wn * 32 + fn * 16 + l16 + k;
                    bfr[fn] = *reinterpret_cast<const bf16x8*>(
                        smem + XT_OFF + r * 256 + (cb ^ ((r & 15) << 4)));
                }
                #pragma unroll
                for (int fm = 0; fm < 4; ++fm)
                    #pragma unroll
                    for (int fn = 0; fn < 2; ++fn)
                        acc[fm][fn] = __builtin_amdgcn_mfma_f32_16x16x32_bf16(
                            af[fm], bfr[fn], acc[fm][fn], 0, 0, 0);
            }
        }

        // ---- write C (f32): row = lg4*4 + j, col = l16 within each fragment
        #pragma unroll
        for (int fm = 0; fm < 4; ++fm) {
            #pragma unroll
            for (int fn = 0; fn < 2; ++fn) {
                const int og = wm * 64 + fm * 16 + lg4 * 4;
                const int lg = l0 + wn * 32 + fn * 16 + l16;
                #pragma unroll
                for (int j = 0; j < 4; ++j)
                    outb[(size_t)(og + j) * NL + lg] = acc[fm][fn][j];
            }
        }

        __syncthreads();                 // all waves done reading XT tile t
        if (tile + 1 < TPB) {
            write_stage();               // XT <- tile t+1 (drains the loads)
            __syncthreads();
        }
    }
}

extern "C" void kernel_launch(void* const* d_in, const int* in_sizes, int n_in,
                              void* d_out, int out_size, void* d_ws, size_t ws_size,
                              hipStream_t stream) {
    const float* x      = (const float*)d_in[0];
    const float* t      = (const float*)d_in[1];
    const float* conv_w = (const float*)d_in[2];
    const float* mod_w  = (const float*)d_in[3];
    const float* mod_b  = (const float*)d_in[4];

    modconv<<<dim3(256), dim3(512), 0, stream>>>(x, t, conv_w, mod_w, mod_b,
                                                 (float*)d_out);
}